// Round 1
// baseline (214.404 us; speedup 1.0000x reference)
//
#include <hip/hip_runtime.h>
#include <math.h>

#define B_ 16384
#define G_ 17
#define K_ 12

// ---------------- Kernel 1: nested-attention history path ----------------
// One block (256 threads) per batch row. Produces hist[b][t][64] in d_ws.
__global__ __launch_bounds__(256) void hist_kernel(
    const float* __restrict__ x_kicks,
    const float* __restrict__ W_ke, const float* __restrict__ b_ke,
    const float* __restrict__ q_inner,
    const float* __restrict__ W_ge, const float* __restrict__ b_ge,
    const float* __restrict__ pos_emb, const float* __restrict__ q_outer,
    const float* __restrict__ log_temp,
    const float* __restrict__ ln_g, const float* __restrict__ ln_b,
    const int* __restrict__ outer_mask, const int* __restrict__ inner_mask,
    float* __restrict__ hist)
{
    __shared__ float s_wke[256];     // W_ke [16][16]
    __shared__ float s_bke[16];
    __shared__ float s_qin[16];
    __shared__ float s_wge[512];     // W_ge [16][32]
    __shared__ float s_bge[32];
    __shared__ float s_pos[17 * 32];
    __shared__ float s_qout[256];    // q_outer [8][32]
    __shared__ float s_scale[8];     // DM^-0.5 * exp(-log_temp[q/2])
    __shared__ float s_kick[204 * 17]; // kick_enc, stride 17 (bank-conflict pad)
    __shared__ float s_sc[204];      // inner scores -> weights
    __shared__ float s_pg[17 * 16];  // per_game
    __shared__ float s_enc[17 * 33]; // encoded, stride 33 (pad)
    __shared__ float s_ao[8 * 17];   // outer scores -> weights
    __shared__ float s_pool[256];    // pooled [8][32] == [4][64]
    __shared__ float s_lng[256], s_lnb[256];

    const int tid = threadIdx.x;
    const int b = blockIdx.x;

    // ---- stage small weights in LDS ----
    s_wke[tid] = W_ke[tid];
    if (tid < 16) { s_bke[tid] = b_ke[tid]; s_qin[tid] = q_inner[tid]; }
    for (int i = tid; i < 512; i += 256) s_wge[i] = W_ge[i];
    if (tid < 32) s_bge[tid] = b_ge[tid];
    for (int i = tid; i < 17 * 32; i += 256) s_pos[i] = pos_emb[i];
    s_qout[tid] = q_outer[tid];
    if (tid < 8) s_scale[tid] = 0.17677669529663687f * __expf(-log_temp[tid >> 1]);
    s_lng[tid] = ln_g[tid]; s_lnb[tid] = ln_b[tid];
    __syncthreads();

    // ---- kick encoder + inner attention scores ----
    if (tid < 204) {
        const int pair = tid;                 // pair = g*12 + k
        const float* xp = x_kicks + ((size_t)b * 204 + pair) * 16;
        float x[16];
        #pragma unroll
        for (int i = 0; i < 4; ++i) {
            float4 v4 = ((const float4*)xp)[i];
            x[4*i+0] = v4.x; x[4*i+1] = v4.y; x[4*i+2] = v4.z; x[4*i+3] = v4.w;
        }
        float sc = 0.f;
        #pragma unroll
        for (int j = 0; j < 16; ++j) {
            float acc = s_bke[j];
            #pragma unroll
            for (int i = 0; i < 16; ++i) acc += x[i] * s_wke[i * 16 + j];
            acc = fmaxf(acc, 0.f);
            s_kick[pair * 17 + j] = acc;
            sc += s_qin[j] * acc;
        }
        sc *= 0.25f;   // DK^-0.5, DK=16
        s_sc[pair] = inner_mask[(size_t)b * 204 + pair] ? sc : -INFINITY;
    }
    __syncthreads();

    // ---- inner softmax (one thread per game) ----
    if (tid < 17) {
        float m = -INFINITY;
        #pragma unroll
        for (int k = 0; k < 12; ++k) m = fmaxf(m, s_sc[tid * 12 + k]);
        float e[12]; float s = 0.f;
        #pragma unroll
        for (int k = 0; k < 12; ++k) {
            float v = (m == -INFINITY) ? 0.f : __expf(s_sc[tid * 12 + k] - m);
            e[k] = v; s += v;
        }
        float inv = (s > 0.f) ? 1.f / s : 0.f;
        #pragma unroll
        for (int k = 0; k < 12; ++k) s_sc[tid * 12 + k] = e[k] * inv;
    }
    __syncthreads();

    // ---- per_game weighted sum [17][16] ----
    for (int idx = tid; idx < 17 * 16; idx += 256) {
        int g = idx >> 4, d = idx & 15;
        float acc = 0.f;
        #pragma unroll
        for (int k = 0; k < 12; ++k)
            acc += s_sc[g * 12 + k] * s_kick[(g * 12 + k) * 17 + d];
        s_pg[idx] = acc;
    }
    __syncthreads();

    // ---- game encoder + pos emb [17][32] ----
    for (int idx = tid; idx < 17 * 32; idx += 256) {
        int g = idx >> 5, d = idx & 31;
        float acc = s_bge[d];
        #pragma unroll
        for (int i = 0; i < 16; ++i) acc += s_pg[g * 16 + i] * s_wge[i * 32 + d];
        s_enc[g * 33 + d] = fmaxf(acc, 0.f) + s_pos[idx];
    }
    __syncthreads();

    // ---- outer attention scores [8][17] ----
    if (tid < 8 * 17) {
        int q = tid / 17, g = tid - q * 17;
        float acc = 0.f;
        #pragma unroll
        for (int d = 0; d < 32; ++d) acc += s_qout[q * 32 + d] * s_enc[g * 33 + d];
        acc *= s_scale[q];
        s_ao[tid] = outer_mask[b * 17 + g] ? acc : -INFINITY;
    }
    __syncthreads();

    // ---- outer softmax (one thread per query) ----
    if (tid < 8) {
        float m = -INFINITY;
        #pragma unroll
        for (int g = 0; g < 17; ++g) m = fmaxf(m, s_ao[tid * 17 + g]);
        float e[17]; float s = 0.f;
        #pragma unroll
        for (int g = 0; g < 17; ++g) {
            float v = (m == -INFINITY) ? 0.f : __expf(s_ao[tid * 17 + g] - m);
            e[g] = v; s += v;
        }
        float inv = (s > 0.f) ? 1.f / s : 0.f;
        #pragma unroll
        for (int g = 0; g < 17; ++g) s_ao[tid * 17 + g] = e[g] * inv;
    }
    __syncthreads();

    // ---- pooled [8][32] (flat == [4][64]) ----
    {
        int q = tid >> 5, d = tid & 31;
        float acc = 0.f;
        #pragma unroll
        for (int g = 0; g < 17; ++g) acc += s_ao[q * 17 + g] * s_enc[g * 33 + d];
        s_pool[tid] = acc;
    }
    __syncthreads();

    // ---- per-target LayerNorm over 64 (each target == one wave) ----
    {
        float v = s_pool[tid];
        float sum = v;
        #pragma unroll
        for (int o = 32; o; o >>= 1) sum += __shfl_xor(sum, o);
        float mu = sum * (1.f / 64.f);
        float dv = v - mu;
        float s2 = dv * dv;
        #pragma unroll
        for (int o = 32; o; o >>= 1) s2 += __shfl_xor(s2, o);
        float rs = rsqrtf(s2 * (1.f / 64.f) + 1e-5f);
        hist[(size_t)b * 256 + tid] = dv * rs * s_lng[tid] + s_lnb[tid];
    }
}

// ---------------- Kernel 2: backbone + per-target heads ----------------
// 16 rows per block, 256 threads.
__global__ __launch_bounds__(256) void backbone_kernel(
    const float* __restrict__ x_static,
    const float* __restrict__ W1, const float* __restrict__ b1,
    const float* __restrict__ g1, const float* __restrict__ be1,
    const float* __restrict__ m1, const float* __restrict__ v1,
    const float* __restrict__ W2, const float* __restrict__ b2,
    const float* __restrict__ g2, const float* __restrict__ be2,
    const float* __restrict__ m2, const float* __restrict__ v2,
    const float* __restrict__ Wh1, const float* __restrict__ bh1,
    const float* __restrict__ Wh2, const float* __restrict__ bh2,
    const float* __restrict__ hist, float* __restrict__ out)
{
    __shared__ float s_x[16 * 64];
    __shared__ float s_z1[16 * 256];
    __shared__ float s_z2[16 * 132];   // stride 132: pad for head-phase reads

    const int tid = threadIdx.x;
    const int row0 = blockIdx.x * 16;

    for (int i = tid; i < 16 * 64; i += 256) s_x[i] = x_static[(size_t)row0 * 64 + i];
    __syncthreads();

    // ---- z1 = relu(BN1(x @ W1)) : one column per thread, 16 rows in regs ----
    {
        const int col = tid;
        float acc[16];
        #pragma unroll
        for (int r = 0; r < 16; ++r) acc[r] = 0.f;
        for (int k = 0; k < 64; ++k) {
            float w = W1[k * 256 + col];
            #pragma unroll
            for (int r = 0; r < 16; ++r) acc[r] += s_x[r * 64 + k] * w;
        }
        float sc = rsqrtf(v1[col] + 1e-5f) * g1[col];
        float off = b1[col] - m1[col];
        float bb = be1[col];
        #pragma unroll
        for (int r = 0; r < 16; ++r)
            s_z1[r * 256 + col] = fmaxf((acc[r] + off) * sc + bb, 0.f);
    }
    __syncthreads();

    // ---- z2 = relu(BN2(z1 @ W2)) : col = tid&127, rows split in halves ----
    {
        const int col = tid & 127;
        const int r0 = (tid >> 7) * 8;
        float acc[8];
        #pragma unroll
        for (int r = 0; r < 8; ++r) acc[r] = 0.f;
        for (int k = 0; k < 256; ++k) {
            float w = W2[k * 128 + col];
            #pragma unroll
            for (int r = 0; r < 8; ++r) acc[r] += s_z1[(r0 + r) * 256 + k] * w;
        }
        float sc = rsqrtf(v2[col] + 1e-5f) * g2[col];
        float off = b2[col] - m2[col];
        float bb = be2[col];
        #pragma unroll
        for (int r = 0; r < 8; ++r)
            s_z2[(r0 + r) * 132 + col] = fmaxf((acc[r] + off) * sc + bb, 0.f);
    }
    __syncthreads();

    // ---- heads: group of 4 lanes per (row,target), 8 hidden units each ----
    {
        const int p = tid >> 2;        // 0..63 : (row, tgt)
        const int gl = tid & 3;        // lane in group
        const int row = p >> 2;        // 0..15
        const int tgt = p & 3;         // 0..3
        const int j0 = gl * 8;

        float acc[8];
        #pragma unroll
        for (int j = 0; j < 8; ++j) acc[j] = bh1[tgt * 32 + j0 + j];

        const float* w1p = Wh1 + (size_t)tgt * 192 * 32 + j0;
        for (int d = 0; d < 128; ++d) {
            float v = s_z2[row * 132 + d];
            float4 a = *(const float4*)(w1p + d * 32);
            float4 c = *(const float4*)(w1p + d * 32 + 4);
            acc[0] += v * a.x; acc[1] += v * a.y; acc[2] += v * a.z; acc[3] += v * a.w;
            acc[4] += v * c.x; acc[5] += v * c.y; acc[6] += v * c.z; acc[7] += v * c.w;
        }
        const float* hp = hist + (size_t)(row0 + row) * 256 + tgt * 64;
        const float* w1q = w1p + 128 * 32;
        for (int d = 0; d < 64; ++d) {
            float v = hp[d];
            float4 a = *(const float4*)(w1q + d * 32);
            float4 c = *(const float4*)(w1q + d * 32 + 4);
            acc[0] += v * a.x; acc[1] += v * a.y; acc[2] += v * a.z; acc[3] += v * a.w;
            acc[4] += v * c.x; acc[5] += v * c.y; acc[6] += v * c.z; acc[7] += v * c.w;
        }
        float ps = 0.f;
        #pragma unroll
        for (int j = 0; j < 8; ++j) ps += fmaxf(acc[j], 0.f) * Wh2[tgt * 32 + j0 + j];
        ps += __shfl_xor(ps, 1);
        ps += __shfl_xor(ps, 2);
        if (gl == 0) out[(size_t)(row0 + row) * 4 + tgt] = fmaxf(ps + bh2[tgt], 0.f);
    }
}

extern "C" void kernel_launch(void* const* d_in, const int* in_sizes, int n_in,
                              void* d_out, int out_size, void* d_ws, size_t ws_size,
                              hipStream_t stream) {
    const float* x_static = (const float*)d_in[0];
    const float* x_kicks  = (const float*)d_in[1];
    const float* W_ke     = (const float*)d_in[2];
    const float* b_ke     = (const float*)d_in[3];
    const float* q_inner  = (const float*)d_in[4];
    const float* W_ge     = (const float*)d_in[5];
    const float* b_ge     = (const float*)d_in[6];
    const float* pos_emb  = (const float*)d_in[7];
    const float* q_outer  = (const float*)d_in[8];
    const float* log_temp = (const float*)d_in[9];
    const float* ln_g     = (const float*)d_in[10];
    const float* ln_b     = (const float*)d_in[11];
    const float* W1       = (const float*)d_in[12];
    const float* b1       = (const float*)d_in[13];
    const float* g1       = (const float*)d_in[14];
    const float* be1      = (const float*)d_in[15];
    const float* m1       = (const float*)d_in[16];
    const float* v1       = (const float*)d_in[17];
    const float* W2       = (const float*)d_in[18];
    const float* b2       = (const float*)d_in[19];
    const float* g2       = (const float*)d_in[20];
    const float* be2      = (const float*)d_in[21];
    const float* m2       = (const float*)d_in[22];
    const float* v2       = (const float*)d_in[23];
    const float* Wh1      = (const float*)d_in[24];
    const float* bh1      = (const float*)d_in[25];
    const float* Wh2      = (const float*)d_in[26];
    const float* bh2      = (const float*)d_in[27];
    const int* outer_mask = (const int*)d_in[28];
    const int* inner_mask = (const int*)d_in[29];

    float* hist = (float*)d_ws;           // 16384 * 4 * 64 floats = 16.8 MB
    float* out  = (float*)d_out;

    hist_kernel<<<B_, 256, 0, stream>>>(
        x_kicks, W_ke, b_ke, q_inner, W_ge, b_ge, pos_emb, q_outer,
        log_temp, ln_g, ln_b, outer_mask, inner_mask, hist);

    backbone_kernel<<<B_ / 16, 256, 0, stream>>>(
        x_static, W1, b1, g1, be1, m1, v1, W2, b2, g2, be2, m2, v2,
        Wh1, bh1, Wh2, bh2, hist, out);
}